// Round 5
// baseline (34.643 us; speedup 1.0000x reference)
//
#include <hip/hip_runtime.h>

#define PSIZE 24
#define NREG 16

// 4 waves per batch item (256-thread block). Physical index
//   p = (w<<10) | (r<<6) | lane,  w = wave 0..3, r = reg 0..15, lane 0..63.
// CNOT chains folded into GF(2) map L (verified R4): L2 rotation on true bit t
// uses stored pair mask e_t|e_{t-1} (e_0 for t=0), role parity(p & bits[t..11]).
// Gates touching wave bits (L1 j=0,1; L2 t=11,10) exchange via swizzled LDS.
__global__ __launch_bounds__(256)
void qsim4(const float* __restrict__ xin,
           const float* __restrict__ W1,
           const float* __restrict__ b1,
           const float* __restrict__ W2,
           const float* __restrict__ b2,
           float* __restrict__ out)
{
    __shared__ float cs[PSIZE], sn[PSIZE];
    __shared__ float xbuf[4 * 64 * NREG];   // 16 KB exchange buffer
    __shared__ float part[4];

    const int tid  = threadIdx.x;
    const int w    = tid >> 6;
    const int lane = tid & 63;
    const int b    = blockIdx.x;

    // fused MLP -> 24 angles -> cos/sin
    if (tid < PSIZE) {
        const float xb = xin[b];
        float acc = b2[tid];
        #pragma unroll
        for (int k = 0; k < 32; ++k) {
            float h = fmaf(xb, W1[k], b1[k]);
            h = fmaxf(h, 0.0f);
            acc = fmaf(h, W2[tid * 32 + k], acc);
        }
        const float half = 0.5f * acc;
        cs[tid] = cosf(half);
        sn[tid] = sinf(half);
    }

    float v[NREG];
    #pragma unroll
    for (int r = 0; r < NREG; ++r) v[r] = 0.0f;
    if (tid == 0) v[0] = 1.0f;                 // p = 0

    const int wb1  = (w >> 1) & 1;             // physical bit 11
    const int wb0  = w & 1;                    // physical bit 10
    const int wpar = wb0 ^ wb1;
    // conflict-free-ish rotation for xbuf (worst case 2-way = free)
    const int rot  = (lane + ((lane >> 4) << 2)) & 15;

    __syncthreads();                           // params ready

    // ============ LAYER 1 ============
    // local reg gates j=2..5 (bits 9..6 = reg bits 3..0), m = 8,4,2,1
    #pragma unroll
    for (int j = 2; j < 6; ++j) {
        const float c = cs[j], s = sn[j];
        const int m = 1 << (5 - j);
        #pragma unroll
        for (int r = 0; r < NREG; ++r) if (!(r & m)) {
            const float a0 = v[r], a1 = v[r | m];
            v[r]     = fmaf(c, a0, -s * a1);
            v[r | m] = fmaf(s, a0,  c * a1);
        }
    }
    // lane gates j=6..11 (bits 5..0), S = 32,16,8,4,2,1
    #pragma unroll
    for (int j = 6; j < 12; ++j) {
        const float c = cs[j], s = sn[j];
        const int S = 1 << (11 - j);
        const float sgn = (lane & S) ? s : -s;
        #pragma unroll
        for (int r = 0; r < NREG; ++r) {
            const float p = __shfl_xor(v[r], S, 64);
            v[r] = fmaf(sgn, p, c * v[r]);
        }
    }
    // j=0 (bit 11): exchange with wave w^2
    {
        __syncthreads();
        #pragma unroll
        for (int r = 0; r < NREG; ++r)
            xbuf[(w << 10) + (lane << 4) + ((r + rot) & 15)] = v[r];
        __syncthreads();
        const float c = cs[0], s = sn[0];
        const float se = wb1 ? s : -s;
        const int pw = w ^ 2;
        #pragma unroll
        for (int r = 0; r < NREG; ++r) {
            const float pv = xbuf[(pw << 10) + (lane << 4) + ((r + rot) & 15)];
            v[r] = fmaf(se, pv, c * v[r]);
        }
    }
    // j=1 (bit 10): exchange with wave w^1
    {
        __syncthreads();
        #pragma unroll
        for (int r = 0; r < NREG; ++r)
            xbuf[(w << 10) + (lane << 4) + ((r + rot) & 15)] = v[r];
        __syncthreads();
        const float c = cs[1], s = sn[1];
        const float se = wb0 ? s : -s;
        const int pw = w ^ 1;
        #pragma unroll
        for (int r = 0; r < NREG; ++r) {
            const float pv = xbuf[(pw << 10) + (lane << 4) + ((r + rot) & 15)];
            v[r] = fmaf(se, pv, c * v[r]);
        }
    }
    // layer-1 CNOT chain: folded

    // ============ LAYER 2 ============
    // t=9 (cs[14]): mask 0xC, rep (r&8)==0; role(rep) = wpar
    {
        const float c = cs[14], s = sn[14];
        const float se = wpar ? s : -s;
        #pragma unroll
        for (int r = 0; r < NREG; ++r) if (!(r & 8)) {
            const float a0 = v[r], a1 = v[r ^ 0xC];
            v[r]       = fmaf( se, a1, c * a0);
            v[r ^ 0xC] = fmaf(-se, a0, c * a1);
        }
    }
    // t=8 (cs[15]): mask 0x6, rep (r&4)==0; role(rep) = bit3(r) ^ wpar
    {
        const float c = cs[15], s = sn[15];
        const float sw = wpar ? s : -s;
        #pragma unroll
        for (int r = 0; r < NREG; ++r) if (!(r & 4)) {
            const float se = (r & 8) ? -sw : sw;
            const float a0 = v[r], a1 = v[r ^ 6];
            v[r]     = fmaf( se, a1, c * a0);
            v[r ^ 6] = fmaf(-se, a0, c * a1);
        }
    }
    // t=7 (cs[16]): mask 0x3, rep (r&2)==0; role(rep) = parity(r&0xC) ^ wpar
    {
        const float c = cs[16], s = sn[16];
        const float sw = wpar ? s : -s;
        #pragma unroll
        for (int r = 0; r < NREG; ++r) if (!(r & 2)) {
            const float se = (__builtin_popcount(r & 0xC) & 1) ? -sw : sw;
            const float a0 = v[r], a1 = v[r ^ 3];
            v[r]     = fmaf( se, a1, c * a0);
            v[r ^ 3] = fmaf(-se, a0, c * a1);
        }
    }
    // t=6 (cs[17]): partner (r^1, lane^32); role = parity(r&0xF) ^ wpar
    {
        const float c = cs[17], s = sn[17];
        const float sw = wpar ? s : -s;
        #pragma unroll
        for (int r = 0; r < NREG; r += 2) {
            const float pe = __shfl_xor(v[r | 1], 32, 64);   // partner of v[r]
            const float po = __shfl_xor(v[r],     32, 64);   // partner of v[r|1]
            const float se = (__builtin_popcount(r) & 1) ? -sw : sw;
            v[r]     = fmaf( se, pe, c * v[r]);
            v[r | 1] = fmaf(-se, po, c * v[r | 1]);
        }
    }
    // t=5..0 (cs[18..23]): lane masks 48,24,12,6,3,1
    #pragma unroll
    for (int g = 0; g < 6; ++g) {
        const float c = cs[18 + g], s = sn[18 + g];
        const int lm   = 48 >> g;
        const int lsuf = (0x3F << (5 - g)) & 0x3F;
        const float sl = ((__popc(lane & lsuf) ^ wpar) & 1) ? s : -s;
        #pragma unroll
        for (int r = 0; r < NREG; ++r) {
            const float p  = __shfl_xor(v[r], lm, 64);
            const float se = (__builtin_popcount(r) & 1) ? -sl : sl;
            v[r] = fmaf(se, p, c * v[r]);
        }
    }
    // t=11 (cs[12]): exchange partner w^3, same r; role = wb1
    {
        __syncthreads();
        #pragma unroll
        for (int r = 0; r < NREG; ++r)
            xbuf[(w << 10) + (lane << 4) + ((r + rot) & 15)] = v[r];
        __syncthreads();
        const float c = cs[12], s = sn[12];
        const float se = wb1 ? s : -s;
        const int pw = w ^ 3;
        #pragma unroll
        for (int r = 0; r < NREG; ++r) {
            const float pv = xbuf[(pw << 10) + (lane << 4) + ((r + rot) & 15)];
            v[r] = fmaf(se, pv, c * v[r]);
        }
    }
    // t=10 (cs[13]): exchange partner (w^1, r^8); role = wpar
    {
        __syncthreads();
        #pragma unroll
        for (int r = 0; r < NREG; ++r)
            xbuf[(w << 10) + (lane << 4) + ((r + rot) & 15)] = v[r];
        __syncthreads();
        const float c = cs[13], s = sn[13];
        const float se = wpar ? s : -s;
        const int pw = w ^ 1;
        #pragma unroll
        for (int r = 0; r < NREG; ++r) {
            const int pr = r ^ 8;
            const float pv = xbuf[(pw << 10) + (lane << 4) + ((pr + rot) & 15)];
            v[r] = fmaf(se, pv, c * v[r]);
        }
    }
    // layer-2 CNOT chain folded: measurement bit = physical bit 11 = wb1

    // <Z_0>
    float acc = 0.0f;
    #pragma unroll
    for (int r = 0; r < NREG; ++r) acc = fmaf(v[r], v[r], acc);
    #pragma unroll
    for (int off = 32; off >= 1; off >>= 1)
        acc += __shfl_xor(acc, off, 64);
    if (lane == 0) part[w] = wb1 ? -acc : acc;
    __syncthreads();
    if (tid == 0) out[b] = (part[0] + part[1]) + (part[2] + part[3]);
}

extern "C" void kernel_launch(void* const* d_in, const int* in_sizes, int n_in,
                              void* d_out, int out_size, void* d_ws, size_t ws_size,
                              hipStream_t stream)
{
    const float* xin = (const float*)d_in[0];
    const float* W1  = (const float*)d_in[1];
    const float* b1  = (const float*)d_in[2];
    const float* W2  = (const float*)d_in[3];
    const float* b2  = (const float*)d_in[4];
    float* out = (float*)d_out;

    qsim4<<<2048, 256, 0, stream>>>(xin, W1, b1, W2, b2, out);
}

// Round 6
// 10.603 us; speedup vs baseline: 3.2673x; 3.2673x over previous
//
#include <hip/hip_runtime.h>

// Heisenberg-picture collapse of the reference circuit.
//
// Observable: z = (+1 for index bit11=0, -1 for bit11=1) == Z on qubit 0.
// Qubit 0 appears ONLY as a control in both CNOT chains, and Z_control
// commutes with CNOT, so the layer-2 chain drops out. Layer-2 rotations on
// qubits != 0 commute with Z_0, and RY(phi)^T Z RY(phi) = cos(phi) Z - sin(phi) X.
// Pulling X_0 back through layer-1's chain: CNOT(0->1)^T X_0 CNOT(0->1) = X_0 X_1.
// Layer-1 rotations: RY^T Z RY = cos t Z - sin t X; RY^T X RY = cos t X + sin t Z.
// On |0...0>: <Z> = 1, <X> = 0. Therefore, with full angles (not halves):
//   out = cos(phi) * cos(theta0) - sin(phi) * sin(theta0) * sin(theta1)
// where theta0 = params[0], theta1 = params[1], phi = params[12]
// (params flat index m = layer*12 + qubit from (h @ W2.T + b2)).
//
// Exact operator identity -> holds for every input; f32 error ~1e-6.

#define BATCH 2048

__global__ __launch_bounds__(256)
void qsim_formula(const float* __restrict__ xin,
                  const float* __restrict__ W1,
                  const float* __restrict__ b1,
                  const float* __restrict__ W2,
                  const float* __restrict__ b2,
                  float* __restrict__ out)
{
    const int i = blockIdx.x * 256 + threadIdx.x;
    if (i >= BATCH) return;

    const float x = xin[i];

    // h_k = relu(x * W1[k] + b1[k]);  p_m = b2[m] + sum_k h_k * W2[m*32+k]
    float p0  = b2[0];     // theta0 = params[layer0, qubit0]
    float p1  = b2[1];     // theta1 = params[layer0, qubit1]
    float p12 = b2[12];    // phi    = params[layer1, qubit0]
    #pragma unroll
    for (int k = 0; k < 32; ++k) {
        const float h = fmaxf(fmaf(x, W1[k], b1[k]), 0.0f);
        p0  = fmaf(h, W2[0 * 32 + k],  p0);
        p1  = fmaf(h, W2[1 * 32 + k],  p1);
        p12 = fmaf(h, W2[12 * 32 + k], p12);
    }

    float s0, c0, sp, cp;
    sincosf(p0,  &s0, &c0);
    sincosf(p12, &sp, &cp);
    const float s1 = sinf(p1);

    out[i] = fmaf(cp, c0, -sp * s0 * s1);
}

extern "C" void kernel_launch(void* const* d_in, const int* in_sizes, int n_in,
                              void* d_out, int out_size, void* d_ws, size_t ws_size,
                              hipStream_t stream)
{
    const float* xin = (const float*)d_in[0];
    const float* W1  = (const float*)d_in[1];
    const float* b1  = (const float*)d_in[2];
    const float* W2  = (const float*)d_in[3];
    const float* b2  = (const float*)d_in[4];
    float* out = (float*)d_out;

    qsim_formula<<<(BATCH + 255) / 256, 256, 0, stream>>>(xin, W1, b1, W2, b2, out);
}